// Round 9
// baseline (4041.009 us; speedup 1.0000x reference)
//
#include <hip/hip_runtime.h>
#include <math.h>

typedef unsigned long long ull;

// LTC liquid scan — batch-amortized GEMM decomposition.
// Grid 256 = 64 batch-tiles x 4 neuron-tiles; block 512 threads, 1 block/CU.
// W_rec slice [128 n][512 k] in VGPRs (128 f/thread). W_in [128][260] LDS.
// Versioned 8-byte mailbox (RELAXED agent atomics, 2 slots by jj parity).
//
// Round-11: OVERLAP the exchange wait with the finish phase. Round-8 showed
// poll TRAFFIC cuts (FETCH 1.64->1.25e6 KB, twice-confirmed) don't cut TIME:
// the wait is latency-bound and sat in a dedicated stage phase where all 8
// waves idled, while the finish phase idled waves 4-7. Fused: during the
// finish of unfold jj (tid<256: reduce+tanh+bypass+publish), waves 4-7
// (tid>=256) poll peers' x_jj remote segments (3 entries/thread) and stage
// them into xsh. The dedicated stage phase is gone; poll RT hides under
// finish; 3 barriers/unfold -> 2. Deadlock induction unchanged (a peer in
// Phase B of jj is polling globally-published version jj -> min-block
// advances; slot-overwrite protected by the same 2-step induction).
// Round-8 (kept): LOCAL BYPASS (finish writes own 128-n segment into xsh;
// only 3 remote segments polled). Guarded spin (2^16 sweeps) -> a hang
// becomes passed:false, not a dead container.
// Round-7 partition (kept): BT=2/NTL=128, grid 256 = 64 bt x 4 nt.
// Round-4 (kept): XOR-swizzle at float4 granularity on xsh/iro/wi.

#define NN 512
#define FF 256
#define KK 6
#define TT 256
#define BT 2         // batches per tile
#define NTL 128      // neurons per tile

#define XROW 512     // xsh row pitch (dwords); conflicts handled by swizzle
#define IPITCH 260   // = 65 float4
#define WIPITCH 260  // = 65 float4
#define PPITCH 17

#define DOT4(a, v) ((a).x * (v).x + (a).y * (v).y + (a).z * (v).z + (a).w * (v).w)

__global__ __launch_bounds__(512, 2) void liquid_kernel(
    const float* __restrict__ I,     // [B][T][F]
    const float* __restrict__ DT,    // [B][T]
    const float* __restrict__ Wrec,  // [N][N]
    const float* __restrict__ Win,   // [N][F]
    const float* __restrict__ bv, const float* __restrict__ Av,
    const float* __restrict__ tauv,
    ull* __restrict__ mbx,           // [64 bt][2 slot][2 b][512 n] versioned
    float* __restrict__ out)         // [B][T][N]
{
  __shared__ __align__(16) float lds[39178];  // 153.0 KB -> 1 block/CU
  float* xsh = lds;                   // [2][512]  x_{jj-1}, swizzled f4 groups
  float* iro = lds + BT * XROW;       // [2][260]  input rows, swizzled
  float* wi  = iro + BT * IPITCH;     // [128][260] W_in slice, swizzled
  float* par = wi + NTL * WIPITCH;    // [256][17] k-chunk partials
  float* dts = par + 256 * PPITCH;    // [2] dt/K per batch

  const int blk = blockIdx.x;
  const int bt  = blk >> 2;          // batch tile (64)
  const int nt  = blk & 3;           // neuron tile (4)
  const int tid = threadIdx.x;
  const int kc  = tid & 15;          // k-chunk (32 k each)
  const int nq  = tid >> 4;          // n-quad (4 n each), 0..31
  const int n0g = nt * NTL;          // global n base of this tile

  // ---- W_rec slice into VGPRs: wv[r][j] = Wrec[n0g+4nq+r][32kc+4j .. +3] ----
  float4 wv[4][8];
  #pragma unroll
  for (int r = 0; r < 4; ++r) {
    const float* wr = Wrec + (size_t)(n0g + nq * 4 + r) * NN + kc * 32;
    #pragma unroll
    for (int j = 0; j < 8; ++j) wv[r][j] = *(const float4*)(wr + 4 * j);
  }
  // ---- W_in slice into LDS (swizzled slot per float4 group) ----
  for (int idx = tid; idx < NTL * FF; idx += 512) {
    const int n = idx >> 8, f = idx & 255;
    const int g = f >> 2, gs = g ^ ((g >> 3) & 7);
    wi[n * WIPITCH + gs * 4 + (f & 3)] = Win[(size_t)(n0g + n) * FF + f];
  }
  // ---- per-(b,n) params + swizzled xo index for finish threads ----
  float rA = 0.f, rIT = 0.f, rB = 0.f;
  int swn = 0;
  if (tid < 256) {
    const int rn = tid & 127;                       // local neuron
    const int n = n0g + rn;
    rA = Av[n]; rIT = 1.0f / tauv[n]; rB = bv[n];
    const int gg = n >> 2;                          // global f4 group
    swn = ((gg ^ ((gg >> 3) & 7)) << 2) | (n & 3);
  }
  // ---- stage-thread constants (tid>=256): 3 remote entries each ----
  int mo0 = 0, mo1 = 0, mo2 = 0;     // mailbox ull offsets within slot
  int lo0 = 0, lo1 = 0, lo2 = 0;     // xsh dword offsets
  if (tid >= 256) {
    const int tp = tid - 256;        // 0..255
    const int sb2 = tp >> 7;         // staged batch row
    const int i3 = (tp & 127) * 3;
    const int n0 = i3 + 0 + ((i3 + 0) >= n0g ? 128 : 0);
    const int n1 = i3 + 1 + ((i3 + 1) >= n0g ? 128 : 0);
    const int n2 = i3 + 2 + ((i3 + 2) >= n0g ? 128 : 0);
    mo0 = sb2 * NN + n0; mo1 = sb2 * NN + n1; mo2 = sb2 * NN + n2;
    const int g0 = n0 >> 2, g1 = n1 >> 2, g2 = n2 >> 2;
    lo0 = sb2 * XROW + (((g0 ^ ((g0 >> 3) & 7)) << 2) | (n0 & 3));
    lo1 = sb2 * XROW + (((g1 ^ ((g1 >> 3) & 7)) << 2) | (n1 & 3));
    lo2 = sb2 * XROW + (((g2 ^ ((g2 >> 3) & 7)) << 2) | (n2 & 3));
  }
  for (int idx = tid; idx < BT * XROW; idx += 512) xsh[idx] = 0.f;  // x0=0

  // ---- thread-constant swizzled addressing (hoisted out of the t-loop) ----
  const int sx  = kc & 7;                           // xsh GEMV read sel
  const int gb  = (kc * 4) ^ ((kc >> 1) & 7);       // wi/iro read slot base
  const float4* xq0 = (const float4*)xsh + kc * 8;  // batch 0
  const float4* xq1 = xq0 + 128;                    // batch 1
  const float4* iq0 = (const float4*)iro;
  const float4* iq1 = iq0 + 65;
  const float4* wq  = (const float4*)wi + (nq * 4) * 65;
  __syncthreads();

  int jj = 0;
  #pragma unroll 1
  for (int t = 0; t < TT; ++t) {
    // ---- stage input rows (swizzled) + dt ----
    if (tid < 2 * 64) {
      const int b = tid >> 6, f4 = tid & 63;
      const int gsi = f4 ^ ((f4 >> 3) & 7);
      ((float4*)iro)[b * 65 + gsi] =
          *(const float4*)&I[((size_t)(bt * BT + b) * TT + t) * FF + f4 * 4];
    }
    if (tid < BT) dts[tid] = DT[(size_t)(bt * BT + tid) * TT + t] * (1.0f / KK);
    __syncthreads();

    // ---- input GEMV partials: inp[b][n] over f in [16kc,16kc+16) ----
    {
      float ai0[4] = {0.f, 0.f, 0.f, 0.f}, ai1[4] = {0.f, 0.f, 0.f, 0.f};
      #pragma unroll
      for (int j2 = 0; j2 < 4; ++j2) {
        const int gg = gb ^ j2;                     // swizzled slot
        float4 w0 = wq[0 * 65 + gg];
        float4 w1 = wq[1 * 65 + gg];
        float4 w2 = wq[2 * 65 + gg];
        float4 w3 = wq[3 * 65 + gg];
        float4 xa = iq0[gg];
        float4 xb = iq1[gg];
        ai0[0] += DOT4(w0, xa); ai0[1] += DOT4(w1, xa);
        ai0[2] += DOT4(w2, xa); ai0[3] += DOT4(w3, xa);
        ai1[0] += DOT4(w0, xb); ai1[1] += DOT4(w1, xb);
        ai1[2] += DOT4(w2, xb); ai1[3] += DOT4(w3, xb);
      }
      #pragma unroll
      for (int r = 0; r < 4; ++r) {
        par[(0 * NTL + nq * 4 + r) * PPITCH + kc] = ai0[r];
        par[(1 * NTL + nq * 4 + r) * PPITCH + kc] = ai1[r];
      }
    }
    __syncthreads();
    float rInp = 0.f, dtk = 0.f;
    if (tid < 256) {
      float s = rB;
      #pragma unroll
      for (int c = 0; c < 16; ++c) s += par[tid * PPITCH + c];
      rInp = s;
      dtk = dts[tid >> 7];
    }
    __syncthreads();  // par free for unfold reuse

    // ---- K unfolds: GEMV -> bar -> [finish || poll+stage] -> bar ----
    #pragma unroll 1
    for (int kk = 0; kk < KK; ++kk) {
      ++jj;  // producing x_jj; consuming x_{jj-1} (already staged in xsh)

      // Phase A: GEMV over k in [32kc,32kc+32), W from VGPRs.
      {
        float acc0[4] = {0.f, 0.f, 0.f, 0.f}, acc1[4] = {0.f, 0.f, 0.f, 0.f};
        #pragma unroll
        for (int j = 0; j < 8; ++j) {
          float4 xv = xq0[j ^ sx];
          acc0[0] += DOT4(wv[0][j], xv); acc0[1] += DOT4(wv[1][j], xv);
          acc0[2] += DOT4(wv[2][j], xv); acc0[3] += DOT4(wv[3][j], xv);
        }
        #pragma unroll
        for (int j = 0; j < 8; ++j) {
          float4 xv = xq1[j ^ sx];
          acc1[0] += DOT4(wv[0][j], xv); acc1[1] += DOT4(wv[1][j], xv);
          acc1[2] += DOT4(wv[2][j], xv); acc1[3] += DOT4(wv[3][j], xv);
        }
        #pragma unroll
        for (int r = 0; r < 4; ++r) {
          par[(0 * NTL + nq * 4 + r) * PPITCH + kc] = acc0[r];
          par[(1 * NTL + nq * 4 + r) * PPITCH + kc] = acc1[r];
        }
      }
      __syncthreads();  // bar1: par ready; xsh[x_{jj-1}] reads done

      // Phase B (wave-uniform split):
      if (tid < 256) {
        // finish: reduce + tanh + bypass + publish (+ out on last unfold)
        float arg = rInp;
        #pragma unroll
        for (int c = 0; c < 16; ++c) arg += par[tid * PPITCH + c];
        const int rb = tid >> 7, rn = tid & 127;
        float f   = tanhf(arg);
        float xo  = xsh[rb * XROW + swn];
        float xn  = fmaf(dtk * f, rA, xo) / fmaf(dtk, rIT + f, 1.0f);
        xsh[rb * XROW + swn] = xn;                  // LOCAL BYPASS (own slot)
        ull w = ((ull)(unsigned)jj << 32) | (ull)__float_as_uint(xn);
        __hip_atomic_store(mbx + (((size_t)bt * 2 + (jj & 1)) << 10) + rb * NN + n0g + rn,
                           w, __ATOMIC_RELAXED, __HIP_MEMORY_SCOPE_AGENT);
        if (kk == KK - 1)
          out[((size_t)(bt * BT + rb) * TT + t) * NN + n0g + rn] = xn;
      } else if (jj < KK * TT) {
        // poll+stage: peers publish x_jj concurrently with our finish.
        const ull* base = mbx + (((size_t)bt * 2 + (jj & 1)) << 10);
        const unsigned want = (unsigned)jj;
        ull v0 = __hip_atomic_load(base + mo0, __ATOMIC_RELAXED, __HIP_MEMORY_SCOPE_AGENT);
        ull v1 = __hip_atomic_load(base + mo1, __ATOMIC_RELAXED, __HIP_MEMORY_SCOPE_AGENT);
        ull v2 = __hip_atomic_load(base + mo2, __ATOMIC_RELAXED, __HIP_MEMORY_SCOPE_AGENT);
        unsigned pend = ((unsigned)(v0 >> 32) != want ? 1u : 0u)
                      | ((unsigned)(v1 >> 32) != want ? 2u : 0u)
                      | ((unsigned)(v2 >> 32) != want ? 4u : 0u);
        int guard = 1 << 16;   // hang-proof: converts deadlock to bad data
        while (pend && --guard) {
          __builtin_amdgcn_s_sleep(1);
          ull w0, w1, w2;
          if (pend & 1u) w0 = __hip_atomic_load(base + mo0, __ATOMIC_RELAXED, __HIP_MEMORY_SCOPE_AGENT);
          if (pend & 2u) w1 = __hip_atomic_load(base + mo1, __ATOMIC_RELAXED, __HIP_MEMORY_SCOPE_AGENT);
          if (pend & 4u) w2 = __hip_atomic_load(base + mo2, __ATOMIC_RELAXED, __HIP_MEMORY_SCOPE_AGENT);
          if ((pend & 1u) && (unsigned)(w0 >> 32) == want) { v0 = w0; pend &= ~1u; }
          if ((pend & 2u) && (unsigned)(w1 >> 32) == want) { v1 = w1; pend &= ~2u; }
          if ((pend & 4u) && (unsigned)(w2 >> 32) == want) { v2 = w2; pend &= ~4u; }
        }
        xsh[lo0] = __uint_as_float((unsigned)v0);
        xsh[lo1] = __uint_as_float((unsigned)v1);
        xsh[lo2] = __uint_as_float((unsigned)v2);
      }
      __syncthreads();  // bar2: xsh holds full x_jj (local bypass + remote)
    }
  }
}

extern "C" void kernel_launch(void* const* d_in, const int* in_sizes, int n_in,
                              void* d_out, int out_size, void* d_ws, size_t ws_size,
                              hipStream_t stream) {
  const float* I    = (const float*)d_in[0];
  const float* DT   = (const float*)d_in[1];
  const float* Wrec = (const float*)d_in[2];
  const float* Win  = (const float*)d_in[3];
  const float* bv   = (const float*)d_in[4];
  const float* Av   = (const float*)d_in[5];
  const float* tauv = (const float*)d_in[6];
  float* out = (float*)d_out;
  ull* mbx = (ull*)d_ws;  // 64*2*2*512*8 B = 1 MB

  liquid_kernel<<<256, 512, 0, stream>>>(I, DT, Wrec, Win, bv, Av, tauv, mbx, out);
}